// Round 14
// baseline (402.613 us; speedup 1.0000x reference)
//
#include <hip/hip_runtime.h>
#include <hip/hip_bf16.h>
#include <hip/hip_cooperative_groups.h>

namespace cg = cooperative_groups;

// GCN: 3x GCNConv (sym-norm, self-loops) + linear head.
// N=50000 nodes, E=800000 edges, F: 128 -> 128 -> 128 -> 64 -> 1.
// Round 14 (from r13 @ 301 us):
//  - CSR build: 5 same-shaped (196x256) kernels merged into ONE cooperative
//    kernel with grid.sync() between phases -- saves 4 launch overheads +
//    inter-dispatch drain. Phases unchanged: hist -> scan1 -> scan2 ->
//    partition(packed u32) -> bucket_csr.
//  - Aggregates: joint gather phase deepened to 4 rows per half-wave
//    (8 in flight per half, 16/wave) -- agg is L3-latency x concurrency
//    bound (3.3M random line fetches); avg degree 16 => one deep iter
//    covers a typical node's half.
// GEMMs (MFMA split-bf16) and everything else unchanged from round 13.

#define N_NODES 50000
#define N_EDGES 800000
#define NBUCK 196          // ceil(N/256) coarse buckets (dst>>8)
#define GB 196             // edge-chunk blocks (== NBUCK, same grid shape)
#define EPB 4096           // edges per block (GB*EPB >= E)

typedef __attribute__((ext_vector_type(8))) short short8;   // 8 bf16 = 4 VGPR
typedef __attribute__((ext_vector_type(4))) float f32x4;    // MFMA C/D

static __device__ __forceinline__ unsigned short f2bf(float f) {
    __hip_bfloat16 h = __float2bfloat16(f);  // RNE
    return *reinterpret_cast<unsigned short*>(&h);
}
static __device__ __forceinline__ float bf2f(unsigned short u) {
    return __uint_as_float(((unsigned)u) << 16);  // exact
}

// ---------- CSR build: one cooperative kernel, 196 blocks x 256 ----------
__global__ __launch_bounds__(256) void csr_build_kernel(
    const int* __restrict__ srcv, const int* __restrict__ dstv,
    int* __restrict__ H, int* __restrict__ bsum, int* __restrict__ bstart,
    unsigned int* __restrict__ P, int* __restrict__ rowoff,
    float* __restrict__ dis, int* __restrict__ csr_src, int n, int nE) {
    cg::grid_group grid = cg::this_grid();
    __shared__ int sh[256];
    __shared__ int sh2[256];
    __shared__ int sh3[256];
    int t = threadIdx.x;
    int b = blockIdx.x;
    int base = b * EPB;

    // ---- phase 1: per-chunk LDS histogram -> H[bucket][block] ----
    for (int i = t; i < NBUCK; i += 256) sh[i] = 0;
    __syncthreads();
#pragma unroll
    for (int i = 0; i < EPB / 256; ++i) {
        int e = base + i * 256 + t;
        if (e < nE) atomicAdd(&sh[dstv[e] >> 8], 1);
    }
    __syncthreads();
    for (int i = t; i < NBUCK; i += 256) H[i * GB + b] = sh[i];
    grid.sync();

    // ---- phase 2: block b scans bucket b's GB chunk-counts ----
    {
        int v = (t < GB) ? H[b * GB + t] : 0;
        sh[t] = v;
        __syncthreads();
        for (int off = 1; off < 256; off <<= 1) {
            int u = (t >= off) ? sh[t - off] : 0;
            __syncthreads();
            sh[t] += u;
            __syncthreads();
        }
        if (t < GB) H[b * GB + t] = sh[t] - v;  // local exclusive
        if (t == 255) bsum[b] = sh[255];
    }
    grid.sync();

    // ---- phase 3: block 0 scans bucket sums -> bstart ----
    if (b == 0) {
        int v = (t < NBUCK) ? bsum[t] : 0;
        sh[t] = v;
        __syncthreads();
        for (int off = 1; off < 256; off <<= 1) {
            int u = (t >= off) ? sh[t - off] : 0;
            __syncthreads();
            sh[t] += u;
            __syncthreads();
        }
        if (t < NBUCK) bstart[t] = sh[t] - v;
        if (t == 0) {
            bstart[NBUCK] = nE;
            rowoff[n] = nE;
        }
    }
    grid.sync();

    // ---- phase 4: scatter packed (src:16 | dst_local:8) into P ----
    for (int i = t; i < NBUCK; i += 256) sh[i] = bstart[i] + H[i * GB + b];
    __syncthreads();
#pragma unroll
    for (int i = 0; i < EPB / 256; ++i) {
        int e = base + i * 256 + t;
        if (e < nE) {
            int d = dstv[e];
            unsigned int pk = (unsigned int)srcv[e] | ((unsigned int)(d & 255) << 16);
            int pos = atomicAdd(&sh[d >> 8], 1);
            P[pos] = pk;
        }
    }
    grid.sync();

    // ---- phase 5: block b builds bucket b's rowoff/dis/csr_src slice ----
    {
        int ebeg = bstart[b], eend = bstart[b + 1];
        sh[t] = 0;
        __syncthreads();
        for (int e = ebeg + t; e < eend; e += 256)
            atomicAdd(&sh[(P[e] >> 16) & 255], 1);
        __syncthreads();
        int myc = sh[t];
        sh2[t] = myc;
        __syncthreads();
        for (int off = 1; off < 256; off <<= 1) {
            int v = (t >= off) ? sh2[t - off] : 0;
            __syncthreads();
            sh2[t] += v;
            __syncthreads();
        }
        int excl = sh2[t] - myc;
        int node = (b << 8) + t;
        if (node < n) {
            rowoff[node] = ebeg + excl;
            dis[node] = rsqrtf((float)(myc + 1));  // +1 self-loop
        }
        sh3[t] = ebeg + excl;
        __syncthreads();
        for (int e = ebeg + t; e < eend; e += 256) {
            unsigned int p = P[e];
            int pos = atomicAdd(&sh3[(p >> 16) & 255], 1);
            csr_src[pos] = (int)(p & 0xFFFFu);
        }
    }
}

// ---------- W prep (fused): W -> transposed bf16 hi/lo [col][k] ----------
__global__ __launch_bounds__(256) void wprep_all_kernel(
    const float* __restrict__ W1, const float* __restrict__ Wh, const float* __restrict__ W2,
    unsigned short* __restrict__ W1hi, unsigned short* __restrict__ W1lo,
    unsigned short* __restrict__ Whhi, unsigned short* __restrict__ Whlo,
    unsigned short* __restrict__ W2hi, unsigned short* __restrict__ W2lo) {
    int t = blockIdx.x * 256 + threadIdx.x;
    const float* W;
    unsigned short *Hi, *Lo;
    int nout, lt;
    if (t < 16384)      { W = W1; Hi = W1hi; Lo = W1lo; nout = 128; lt = t; }
    else if (t < 32768) { W = Wh; Hi = Whhi; Lo = Whlo; nout = 128; lt = t - 16384; }
    else if (t < 40960) { W = W2; Hi = W2hi; Lo = W2lo; nout = 64;  lt = t - 32768; }
    else return;
    int col = lt % nout, k = lt / nout;
    float v = W[lt];                       // coalesced (lt == k*nout+col)
    unsigned short hi = f2bf(v);
    unsigned short lo = f2bf(v - bf2f(hi));
    Hi[(size_t)col * 128 + k] = hi;
    Lo[(size_t)col * 128 + k] = lo;
}

// ---------- MFMA GEMM: C[r] = bf16((A[r] @ W) * scale[r]) ----------
// Block = 64 rows x 64 cols, 4 waves. B hi/lo in regs (loaded once per wave),
// A hi/lo in LDS (34 KB). Split-bf16 x3: Ah*Bh + Ah*Bl + Al*Bh.
template <int NOUT>
__global__ __launch_bounds__(256) void gemm_mfma_kernel(
    const float* __restrict__ A,
    const unsigned short* __restrict__ Wthi,  // [NOUT][128] bf16
    const unsigned short* __restrict__ Wtlo,
    const float* __restrict__ scale,
    unsigned short* __restrict__ C, int M) {
    constexpr int LDK = 136;  // shorts; 16 B-aligned frags, banks spread
    __shared__ unsigned short sAhi[64 * LDK];
    __shared__ unsigned short sAlo[64 * LDK];

    int tid = threadIdx.x;
    int w = tid >> 6, lane = tid & 63;
    int quad = lane >> 4, m = lane & 15;
    int Rbase = blockIdx.x * 64;
    int Cbase = blockIdx.y * 64;
    int r0 = (w & 1) * 32, c0 = (w >> 1) * 32;

    short8 bh[4][2], bl[4][2];
#pragma unroll
    for (int ks = 0; ks < 4; ++ks)
#pragma unroll
        for (int g = 0; g < 2; ++g) {
            size_t off = (size_t)(Cbase + c0 + g * 16 + m) * 128 + ks * 32 + quad * 8;
            bh[ks][g] = *(const short8*)(Wthi + off);
            bl[ks][g] = *(const short8*)(Wtlo + off);
        }

    for (int i = tid; i < 64 * 32; i += 256) {
        int r = i >> 5, c4 = i & 31;
        int row = Rbase + r;
        float4 v = make_float4(0.f, 0.f, 0.f, 0.f);
        if (row < M) v = ((const float4*)(A + (size_t)row * 128))[c4];
        ushort4 hi, lo;
        hi.x = f2bf(v.x); lo.x = f2bf(v.x - bf2f(hi.x));
        hi.y = f2bf(v.y); lo.y = f2bf(v.y - bf2f(hi.y));
        hi.z = f2bf(v.z); lo.z = f2bf(v.z - bf2f(hi.z));
        hi.w = f2bf(v.w); lo.w = f2bf(v.w - bf2f(hi.w));
        *(ushort4*)(sAhi + r * LDK + c4 * 4) = hi;
        *(ushort4*)(sAlo + r * LDK + c4 * 4) = lo;
    }
    __syncthreads();

    f32x4 z = {0.f, 0.f, 0.f, 0.f};
    f32x4 acc00 = z, acc01 = z, acc10 = z, acc11 = z;

#pragma unroll
    for (int ks = 0; ks < 4; ++ks) {
        int kof = ks * 32 + quad * 8;
        short8 ah0 = *(const short8*)(sAhi + (r0 + m) * LDK + kof);
        short8 ah1 = *(const short8*)(sAhi + (r0 + 16 + m) * LDK + kof);
        short8 al0 = *(const short8*)(sAlo + (r0 + m) * LDK + kof);
        short8 al1 = *(const short8*)(sAlo + (r0 + 16 + m) * LDK + kof);
        acc00 = __builtin_amdgcn_mfma_f32_16x16x32_bf16(ah0, bh[ks][0], acc00, 0, 0, 0);
        acc01 = __builtin_amdgcn_mfma_f32_16x16x32_bf16(ah0, bh[ks][1], acc01, 0, 0, 0);
        acc10 = __builtin_amdgcn_mfma_f32_16x16x32_bf16(ah1, bh[ks][0], acc10, 0, 0, 0);
        acc11 = __builtin_amdgcn_mfma_f32_16x16x32_bf16(ah1, bh[ks][1], acc11, 0, 0, 0);
        acc00 = __builtin_amdgcn_mfma_f32_16x16x32_bf16(ah0, bl[ks][0], acc00, 0, 0, 0);
        acc01 = __builtin_amdgcn_mfma_f32_16x16x32_bf16(ah0, bl[ks][1], acc01, 0, 0, 0);
        acc10 = __builtin_amdgcn_mfma_f32_16x16x32_bf16(ah1, bl[ks][0], acc10, 0, 0, 0);
        acc11 = __builtin_amdgcn_mfma_f32_16x16x32_bf16(ah1, bl[ks][1], acc11, 0, 0, 0);
        acc00 = __builtin_amdgcn_mfma_f32_16x16x32_bf16(al0, bh[ks][0], acc00, 0, 0, 0);
        acc01 = __builtin_amdgcn_mfma_f32_16x16x32_bf16(al0, bh[ks][1], acc01, 0, 0, 0);
        acc10 = __builtin_amdgcn_mfma_f32_16x16x32_bf16(al1, bh[ks][0], acc10, 0, 0, 0);
        acc11 = __builtin_amdgcn_mfma_f32_16x16x32_bf16(al1, bh[ks][1], acc11, 0, 0, 0);
    }

#pragma unroll
    for (int reg = 0; reg < 4; ++reg) {
        int row0g = Rbase + r0 + quad * 4 + reg;
        if (row0g < M) {
            float sc = scale[row0g];
            C[(size_t)row0g * NOUT + Cbase + c0 + m]      = f2bf(acc00[reg] * sc);
            C[(size_t)row0g * NOUT + Cbase + c0 + 16 + m] = f2bf(acc01[reg] * sc);
        }
        int row1g = row0g + 16;
        if (row1g < M) {
            float sc = scale[row1g];
            C[(size_t)row1g * NOUT + Cbase + c0 + m]      = f2bf(acc10[reg] * sc);
            C[(size_t)row1g * NOUT + Cbase + c0 + 16 + m] = f2bf(acc11[reg] * sc);
        }
    }
}

// ---------- Gather aggregation: half-wave row gather, 2 nodes per wave ------
// 32 lanes x ushort4 (8 B) = one full 256 B row per half-wave.
// Joint phase 4-deep: 8 rows in flight per half (16/wave).
__global__ __launch_bounds__(256) void aggregate128_kernel(
    const int* __restrict__ rowoff, const int* __restrict__ csr_src,
    const float* __restrict__ dis, const unsigned short* __restrict__ tp,
    const float* __restrict__ bias, float* __restrict__ hout, int n) {
    int wid = (blockIdx.x * 256 + threadIdx.x) >> 6;
    int lane = threadIdx.x & 63;
    int h = lane >> 5, lc = lane & 31;
    int n0 = wid * 2;
    if (n0 >= n) return;
    int n1 = n0 + 1;
    bool has1 = (n1 < n);

    float a0[4] = {0.f, 0.f, 0.f, 0.f};
    float a1[4] = {0.f, 0.f, 0.f, 0.f};

#define ROW128(node) (*((const ushort4*)(tp + (size_t)(node) * 128) + lc))
#define ACC(a, u) { a[0] += bf2f(u.x); a[1] += bf2f(u.y); a[2] += bf2f(u.z); a[3] += bf2f(u.w); }

    if (h == 0) { ushort4 u = ROW128(n0); ACC(a0, u); }
    else if (has1) { ushort4 u = ROW128(n1); ACC(a1, u); }

    int mid = rowoff[n0 + 1];
    int i0 = rowoff[n0] + h;
    int i1 = mid + h;
    int end1 = has1 ? rowoff[n1 + 1] : mid;

    // 4-deep joint: 8 rows in flight per half
    while (i0 + 6 < mid && i1 + 6 < end1) {
        int p0 = csr_src[i0], p1 = csr_src[i0 + 2], p2 = csr_src[i0 + 4], p3 = csr_src[i0 + 6];
        int q0 = csr_src[i1], q1 = csr_src[i1 + 2], q2 = csr_src[i1 + 4], q3 = csr_src[i1 + 6];
        ushort4 u0 = ROW128(p0), u1 = ROW128(p1), u2 = ROW128(p2), u3 = ROW128(p3);
        ushort4 v0 = ROW128(q0), v1 = ROW128(q1), v2 = ROW128(q2), v3 = ROW128(q3);
        ACC(a0, u0); ACC(a0, u1); ACC(a0, u2); ACC(a0, u3);
        ACC(a1, v0); ACC(a1, v1); ACC(a1, v2); ACC(a1, v3);
        i0 += 8; i1 += 8;
    }
    // 2-deep joint
    while (i0 + 2 < mid && i1 + 2 < end1) {
        int p0 = csr_src[i0], p1 = csr_src[i0 + 2];
        int q0 = csr_src[i1], q1 = csr_src[i1 + 2];
        ushort4 u0 = ROW128(p0), u1 = ROW128(p1);
        ushort4 v0 = ROW128(q0), v1 = ROW128(q1);
        ACC(a0, u0); ACC(a0, u1);
        ACC(a1, v0); ACC(a1, v1);
        i0 += 4; i1 += 4;
    }
    // drains
    for (; i0 + 2 < mid; i0 += 4) {
        int p0 = csr_src[i0], p1 = csr_src[i0 + 2];
        ushort4 u0 = ROW128(p0), u1 = ROW128(p1);
        ACC(a0, u0); ACC(a0, u1);
    }
    for (; i0 < mid; i0 += 2) { ushort4 u = ROW128(csr_src[i0]); ACC(a0, u); }
    for (; i1 + 2 < end1; i1 += 4) {
        int q0 = csr_src[i1], q1 = csr_src[i1 + 2];
        ushort4 v0 = ROW128(q0), v1 = ROW128(q1);
        ACC(a1, v0); ACC(a1, v1);
    }
    for (; i1 < end1; i1 += 2) { ushort4 v = ROW128(csr_src[i1]); ACC(a1, v); }
#undef ROW128
#undef ACC

#pragma unroll
    for (int j = 0; j < 4; ++j) {
        a0[j] += __shfl_xor(a0[j], 32);
        a1[j] += __shfl_xor(a1[j], 32);
    }

    float4 b = ((const float4*)bias)[lc];
    if (h == 0) {
        float dd = dis[n0];
        float4 r;
        r.x = fmaxf(a0[0] * dd + b.x, 0.f);
        r.y = fmaxf(a0[1] * dd + b.y, 0.f);
        r.z = fmaxf(a0[2] * dd + b.z, 0.f);
        r.w = fmaxf(a0[3] * dd + b.w, 0.f);
        ((float4*)(hout + (size_t)n0 * 128))[lc] = r;
    } else if (has1) {
        float dd = dis[n1];
        float4 r;
        r.x = fmaxf(a1[0] * dd + b.x, 0.f);
        r.y = fmaxf(a1[1] * dd + b.y, 0.f);
        r.z = fmaxf(a1[2] * dd + b.z, 0.f);
        r.w = fmaxf(a1[3] * dd + b.w, 0.f);
        ((float4*)(hout + (size_t)n1 * 128))[lc] = r;
    }
}

// F=64 + fused head. 32 lanes x ushort2 (4 B) = one 128 B row per half.
__global__ __launch_bounds__(256) void aggregate64_head_kernel(
    const int* __restrict__ rowoff, const int* __restrict__ csr_src,
    const float* __restrict__ dis, const unsigned short* __restrict__ tp,
    const float* __restrict__ bias, const float* __restrict__ Wout,
    const float* __restrict__ bout, float* __restrict__ hout,
    float* __restrict__ out, int n) {
    int wid = (blockIdx.x * 256 + threadIdx.x) >> 6;
    int lane = threadIdx.x & 63;
    int h = lane >> 5, lc = lane & 31;
    int n0 = wid * 2;
    if (n0 >= n) return;
    int n1 = n0 + 1;
    bool has1 = (n1 < n);

    float a0[2] = {0.f, 0.f};
    float a1[2] = {0.f, 0.f};

#define ROW64(node) (*((const ushort2*)(tp + (size_t)(node) * 64) + lc))
#define ACC2(a, u) { a[0] += bf2f(u.x); a[1] += bf2f(u.y); }

    if (h == 0) { ushort2 u = ROW64(n0); ACC2(a0, u); }
    else if (has1) { ushort2 u = ROW64(n1); ACC2(a1, u); }

    int mid = rowoff[n0 + 1];
    int i0 = rowoff[n0] + h;
    int i1 = mid + h;
    int end1 = has1 ? rowoff[n1 + 1] : mid;

    while (i0 + 6 < mid && i1 + 6 < end1) {
        int p0 = csr_src[i0], p1 = csr_src[i0 + 2], p2 = csr_src[i0 + 4], p3 = csr_src[i0 + 6];
        int q0 = csr_src[i1], q1 = csr_src[i1 + 2], q2 = csr_src[i1 + 4], q3 = csr_src[i1 + 6];
        ushort2 u0 = ROW64(p0), u1 = ROW64(p1), u2 = ROW64(p2), u3 = ROW64(p3);
        ushort2 v0 = ROW64(q0), v1 = ROW64(q1), v2 = ROW64(q2), v3 = ROW64(q3);
        ACC2(a0, u0); ACC2(a0, u1); ACC2(a0, u2); ACC2(a0, u3);
        ACC2(a1, v0); ACC2(a1, v1); ACC2(a1, v2); ACC2(a1, v3);
        i0 += 8; i1 += 8;
    }
    while (i0 + 2 < mid && i1 + 2 < end1) {
        int p0 = csr_src[i0], p1 = csr_src[i0 + 2];
        int q0 = csr_src[i1], q1 = csr_src[i1 + 2];
        ushort2 u0 = ROW64(p0), u1 = ROW64(p1);
        ushort2 v0 = ROW64(q0), v1 = ROW64(q1);
        ACC2(a0, u0); ACC2(a0, u1);
        ACC2(a1, v0); ACC2(a1, v1);
        i0 += 4; i1 += 4;
    }
    for (; i0 < mid; i0 += 2) { ushort2 u = ROW64(csr_src[i0]); ACC2(a0, u); }
    for (; i1 < end1; i1 += 2) { ushort2 v = ROW64(csr_src[i1]); ACC2(a1, v); }
#undef ROW64
#undef ACC2

#pragma unroll
    for (int j = 0; j < 2; ++j) {
        a0[j] += __shfl_xor(a0[j], 32);
        a1[j] += __shfl_xor(a1[j], 32);
    }

    int node = h ? n1 : n0;
    float* ap = h ? a1 : a0;
    bool valid = (h == 0) || has1;
    float2 hv = make_float2(0.f, 0.f);
    if (valid) {
        float dd = dis[node];
        float2 b = ((const float2*)bias)[lc];
        hv.x = ap[0] * dd + b.x;
        hv.y = ap[1] * dd + b.y;
        ((float2*)(hout + (size_t)node * 64))[lc] = hv;
    }
    float2 wv = ((const float2*)Wout)[lc];
    float p = valid ? (hv.x * wv.x + hv.y * wv.y) : 0.f;
#pragma unroll
    for (int off = 16; off > 0; off >>= 1) p += __shfl_down(p, off);
    if (lc == 0 && valid) out[node] = p + bout[0];
}

extern "C" void kernel_launch(void* const* d_in, const int* in_sizes, int n_in,
                              void* d_out, int out_size, void* d_ws, size_t ws_size,
                              hipStream_t stream) {
    const float* x    = (const float*)d_in[0];
    const int*   ei   = (const int*)d_in[1];  // [2, E] flat: src then dst
    const float* W1   = (const float*)d_in[2];
    const float* b1   = (const float*)d_in[3];
    const float* Wh   = (const float*)d_in[4];
    const float* bh   = (const float*)d_in[5];
    const float* W2   = (const float*)d_in[6];
    const float* b2   = (const float*)d_in[7];
    const float* Wout = (const float*)d_in[8];
    const float* bout = (const float*)d_in[9];

    int N = N_NODES;
    int E = N_EDGES;
    const int* srcv = ei;
    const int* dstv = ei + E;

    float* out  = (float*)d_out;            // [N]
    float* hout = (float*)d_out + N;        // [N x 64]

    char* ws = (char*)d_ws;
    int*   H       = (int*)ws;                          ws += sizeof(int) * NBUCK * GB;
    int*   bsum    = (int*)ws;                          ws += sizeof(int) * NBUCK;
    int*   bstart  = (int*)ws;                          ws += sizeof(int) * (NBUCK + 1);
    int*   rowoff  = (int*)ws;                          ws += sizeof(int) * (N + 1);
    unsigned int* P = (unsigned int*)ws;                ws += sizeof(unsigned int) * E;
    int*   csr_src = (int*)ws;                          ws += sizeof(int) * E;
    float* dis     = (float*)ws;                        ws += sizeof(float) * N;
    unsigned short* W1thi = (unsigned short*)ws;        ws += sizeof(unsigned short) * 128 * 128;
    unsigned short* W1tlo = (unsigned short*)ws;        ws += sizeof(unsigned short) * 128 * 128;
    unsigned short* Whthi = (unsigned short*)ws;        ws += sizeof(unsigned short) * 128 * 128;
    unsigned short* Whtlo = (unsigned short*)ws;        ws += sizeof(unsigned short) * 128 * 128;
    unsigned short* W2thi = (unsigned short*)ws;        ws += sizeof(unsigned short) * 64 * 128;
    unsigned short* W2tlo = (unsigned short*)ws;        ws += sizeof(unsigned short) * 64 * 128;
    unsigned short* bufT  = (unsigned short*)ws;        ws += sizeof(unsigned short) * (size_t)N * 128;
    float* bufH    = (float*)ws;                        // N*128 fp32

    // --- W prep (fused, bf16 hi/lo transposed) ---
    wprep_all_kernel<<<160, 256, 0, stream>>>(W1, Wh, W2, W1thi, W1tlo, Whthi, Whtlo, W2thi, W2tlo);

    // --- CSR build: single cooperative kernel (196 blocks x 256) ---
    {
        void* args[] = {
            (void*)&srcv, (void*)&dstv, (void*)&H, (void*)&bsum, (void*)&bstart,
            (void*)&P, (void*)&rowoff, (void*)&dis, (void*)&csr_src,
            (void*)&N, (void*)&E
        };
        hipLaunchCooperativeKernel((const void*)csr_build_kernel,
                                   dim3(GB), dim3(256), args, 0, stream);
    }

    const int aggBlocks = ((N + 1) / 2 * 64 + 255) / 256;  // 2 nodes per wave
    const int gemmRows = (N + 63) / 64;                    // 782

    // --- layer 1: h1 = relu(agg(x@W1) + b1) ---
    gemm_mfma_kernel<128><<<dim3(gemmRows, 2), 256, 0, stream>>>(x, W1thi, W1tlo, dis, bufT, N);
    aggregate128_kernel<<<aggBlocks, 256, 0, stream>>>(rowoff, csr_src, dis, bufT, b1, bufH, N);

    // --- layer 2: h2 = relu(agg(h1@Wh) + bh) ---
    gemm_mfma_kernel<128><<<dim3(gemmRows, 2), 256, 0, stream>>>(bufH, Whthi, Whtlo, dis, bufT, N);
    aggregate128_kernel<<<aggBlocks, 256, 0, stream>>>(rowoff, csr_src, dis, bufT, bh, bufH, N);

    // --- layer 3 + head: h3 = agg(h2@W2) + b2 ; out = h3@Wout + bout ---
    gemm_mfma_kernel<64><<<dim3(gemmRows, 1), 256, 0, stream>>>(bufH, W2thi, W2tlo, dis, bufT, N);
    aggregate64_head_kernel<<<aggBlocks, 256, 0, stream>>>(
        rowoff, csr_src, dis, bufT, b2, Wout, bout, hout, out, N);
}

// Round 15
// 296.689 us; speedup vs baseline: 1.3570x; 1.3570x over previous
//
#include <hip/hip_runtime.h>
#include <hip/hip_bf16.h>

// GCN: 3x GCNConv (sym-norm, self-loops) + linear head.
// N=50000 nodes, E=800000 edges, F: 128 -> 128 -> 128 -> 64 -> 1.
// Round 15: revert r14's cooperative CSR build (grid.sync costs ~20us each
// across 8 non-coherent XCD L2s -> 115us vs 45us for 5 separate launches;
// occupancy 8.7%). Back to round-13 five-kernel build (packed u32 pairs).
// Kept from r14: 4-deep aggregate joint phase (8 rows in flight per half).
// Established floors: agg = cross-XCD compulsory traffic (113 MB, ~44us);
// gemm = MFMA split-bf16 x3; build = LDS-bucketed counting sort.
// Disproven: panels (r10/r11, instruction cost > memory win), phase fusion
// (r12, kills gather TLP), coop build (r14, grid.sync cost).

#define N_NODES 50000
#define N_EDGES 800000
#define NBUCK 196          // ceil(N/256) coarse buckets (dst>>8)
#define GB 196             // edge-chunk blocks
#define EPB 4096           // edges per block (GB*EPB >= E)

typedef __attribute__((ext_vector_type(8))) short short8;   // 8 bf16 = 4 VGPR
typedef __attribute__((ext_vector_type(4))) float f32x4;    // MFMA C/D

static __device__ __forceinline__ unsigned short f2bf(float f) {
    __hip_bfloat16 h = __float2bfloat16(f);  // RNE
    return *reinterpret_cast<unsigned short*>(&h);
}
static __device__ __forceinline__ float bf2f(unsigned short u) {
    return __uint_as_float(((unsigned)u) << 16);  // exact
}

// ---------- CSR build: two-level counting sort (5 kernels, r13 form) -------

__global__ __launch_bounds__(256) void hist_kernel(const int* __restrict__ dstv,
                                                   int* __restrict__ H, int nE) {
    __shared__ int h[NBUCK];
    for (int i = threadIdx.x; i < NBUCK; i += 256) h[i] = 0;
    __syncthreads();
    int base = blockIdx.x * EPB;
#pragma unroll
    for (int i = 0; i < EPB / 256; ++i) {
        int e = base + i * 256 + threadIdx.x;
        if (e < nE) atomicAdd(&h[dstv[e] >> 8], 1);
    }
    __syncthreads();
    for (int i = threadIdx.x; i < NBUCK; i += 256)
        H[i * GB + blockIdx.x] = h[i];   // bucket-major
}

__global__ __launch_bounds__(256) void scan1_kernel(int* __restrict__ H,
                                                    int* __restrict__ bsum) {
    __shared__ int s[256];
    int t = threadIdx.x;
    int k = blockIdx.x;
    int v = (t < GB) ? H[k * GB + t] : 0;
    s[t] = v;
    __syncthreads();
    for (int off = 1; off < 256; off <<= 1) {
        int u = (t >= off) ? s[t - off] : 0;
        __syncthreads();
        s[t] += u;
        __syncthreads();
    }
    if (t < GB) H[k * GB + t] = s[t] - v;  // local exclusive
    if (t == 255) bsum[k] = s[255];
}

__global__ __launch_bounds__(256) void scan2_kernel(const int* __restrict__ bsum,
                                                    int* __restrict__ bstart,
                                                    int* __restrict__ rowoff_last) {
    __shared__ int s[256];
    int t = threadIdx.x;
    int v = (t < NBUCK) ? bsum[t] : 0;
    s[t] = v;
    __syncthreads();
    for (int off = 1; off < 256; off <<= 1) {
        int u = (t >= off) ? s[t - off] : 0;
        __syncthreads();
        s[t] += u;
        __syncthreads();
    }
    if (t < NBUCK) bstart[t] = s[t] - v;  // exclusive
    if (t == 0) {
        bstart[NBUCK] = N_EDGES;
        *rowoff_last = N_EDGES;
    }
}

// Scatter packed (src:16 | dst_local:8) into bucket-partitioned P.
__global__ __launch_bounds__(256) void partition_kernel(const int* __restrict__ srcv,
                                                        const int* __restrict__ dstv,
                                                        const int* __restrict__ H,
                                                        const int* __restrict__ bstart,
                                                        unsigned int* __restrict__ P, int nE) {
    __shared__ int cur[NBUCK];
    for (int i = threadIdx.x; i < NBUCK; i += 256)
        cur[i] = bstart[i] + H[i * GB + blockIdx.x];
    __syncthreads();
    int base = blockIdx.x * EPB;
#pragma unroll
    for (int i = 0; i < EPB / 256; ++i) {
        int e = base + i * 256 + threadIdx.x;
        if (e < nE) {
            int d = dstv[e];
            unsigned int pk = (unsigned int)srcv[e] | ((unsigned int)(d & 255) << 16);
            int pos = atomicAdd(&cur[d >> 8], 1);
            P[pos] = pk;
        }
    }
}

__global__ __launch_bounds__(256) void bucket_csr_kernel(const unsigned int* __restrict__ P,
                                                         const int* __restrict__ bstart,
                                                         int* __restrict__ rowoff,
                                                         float* __restrict__ dis,
                                                         int* __restrict__ csr_src, int n) {
    __shared__ int cnt[256];
    __shared__ int s[256];
    __shared__ int cur[256];
    int t = threadIdx.x;
    int k = blockIdx.x;
    int ebeg = bstart[k], eend = bstart[k + 1];
    cnt[t] = 0;
    __syncthreads();
    for (int e = ebeg + t; e < eend; e += 256)
        atomicAdd(&cnt[(P[e] >> 16) & 255], 1);
    __syncthreads();
    int myc = cnt[t];
    s[t] = myc;
    __syncthreads();
    for (int off = 1; off < 256; off <<= 1) {
        int v = (t >= off) ? s[t - off] : 0;
        __syncthreads();
        s[t] += v;
        __syncthreads();
    }
    int excl = s[t] - myc;
    int node = (k << 8) + t;
    if (node < n) {
        rowoff[node] = ebeg + excl;
        dis[node] = rsqrtf((float)(myc + 1));  // +1 self-loop
    }
    cur[t] = ebeg + excl;
    __syncthreads();
    for (int e = ebeg + t; e < eend; e += 256) {
        unsigned int p = P[e];
        int pos = atomicAdd(&cur[(p >> 16) & 255], 1);
        csr_src[pos] = (int)(p & 0xFFFFu);
    }
}

// ---------- W prep (fused): W -> transposed bf16 hi/lo [col][k] ----------
__global__ __launch_bounds__(256) void wprep_all_kernel(
    const float* __restrict__ W1, const float* __restrict__ Wh, const float* __restrict__ W2,
    unsigned short* __restrict__ W1hi, unsigned short* __restrict__ W1lo,
    unsigned short* __restrict__ Whhi, unsigned short* __restrict__ Whlo,
    unsigned short* __restrict__ W2hi, unsigned short* __restrict__ W2lo) {
    int t = blockIdx.x * 256 + threadIdx.x;
    const float* W;
    unsigned short *Hi, *Lo;
    int nout, lt;
    if (t < 16384)      { W = W1; Hi = W1hi; Lo = W1lo; nout = 128; lt = t; }
    else if (t < 32768) { W = Wh; Hi = Whhi; Lo = Whlo; nout = 128; lt = t - 16384; }
    else if (t < 40960) { W = W2; Hi = W2hi; Lo = W2lo; nout = 64;  lt = t - 32768; }
    else return;
    int col = lt % nout, k = lt / nout;
    float v = W[lt];                       // coalesced (lt == k*nout+col)
    unsigned short hi = f2bf(v);
    unsigned short lo = f2bf(v - bf2f(hi));
    Hi[(size_t)col * 128 + k] = hi;
    Lo[(size_t)col * 128 + k] = lo;
}

// ---------- MFMA GEMM: C[r] = bf16((A[r] @ W) * scale[r]) ----------
// Block = 64 rows x 64 cols, 4 waves. B hi/lo in regs (loaded once per wave),
// A hi/lo in LDS (34 KB). Split-bf16 x3: Ah*Bh + Ah*Bl + Al*Bh.
template <int NOUT>
__global__ __launch_bounds__(256) void gemm_mfma_kernel(
    const float* __restrict__ A,
    const unsigned short* __restrict__ Wthi,  // [NOUT][128] bf16
    const unsigned short* __restrict__ Wtlo,
    const float* __restrict__ scale,
    unsigned short* __restrict__ C, int M) {
    constexpr int LDK = 136;  // shorts; 16 B-aligned frags, banks spread
    __shared__ unsigned short sAhi[64 * LDK];
    __shared__ unsigned short sAlo[64 * LDK];

    int tid = threadIdx.x;
    int w = tid >> 6, lane = tid & 63;
    int quad = lane >> 4, m = lane & 15;
    int Rbase = blockIdx.x * 64;
    int Cbase = blockIdx.y * 64;
    int r0 = (w & 1) * 32, c0 = (w >> 1) * 32;

    short8 bh[4][2], bl[4][2];
#pragma unroll
    for (int ks = 0; ks < 4; ++ks)
#pragma unroll
        for (int g = 0; g < 2; ++g) {
            size_t off = (size_t)(Cbase + c0 + g * 16 + m) * 128 + ks * 32 + quad * 8;
            bh[ks][g] = *(const short8*)(Wthi + off);
            bl[ks][g] = *(const short8*)(Wtlo + off);
        }

    for (int i = tid; i < 64 * 32; i += 256) {
        int r = i >> 5, c4 = i & 31;
        int row = Rbase + r;
        float4 v = make_float4(0.f, 0.f, 0.f, 0.f);
        if (row < M) v = ((const float4*)(A + (size_t)row * 128))[c4];
        ushort4 hi, lo;
        hi.x = f2bf(v.x); lo.x = f2bf(v.x - bf2f(hi.x));
        hi.y = f2bf(v.y); lo.y = f2bf(v.y - bf2f(hi.y));
        hi.z = f2bf(v.z); lo.z = f2bf(v.z - bf2f(hi.z));
        hi.w = f2bf(v.w); lo.w = f2bf(v.w - bf2f(hi.w));
        *(ushort4*)(sAhi + r * LDK + c4 * 4) = hi;
        *(ushort4*)(sAlo + r * LDK + c4 * 4) = lo;
    }
    __syncthreads();

    f32x4 z = {0.f, 0.f, 0.f, 0.f};
    f32x4 acc00 = z, acc01 = z, acc10 = z, acc11 = z;

#pragma unroll
    for (int ks = 0; ks < 4; ++ks) {
        int kof = ks * 32 + quad * 8;
        short8 ah0 = *(const short8*)(sAhi + (r0 + m) * LDK + kof);
        short8 ah1 = *(const short8*)(sAhi + (r0 + 16 + m) * LDK + kof);
        short8 al0 = *(const short8*)(sAlo + (r0 + m) * LDK + kof);
        short8 al1 = *(const short8*)(sAlo + (r0 + 16 + m) * LDK + kof);
        acc00 = __builtin_amdgcn_mfma_f32_16x16x32_bf16(ah0, bh[ks][0], acc00, 0, 0, 0);
        acc01 = __builtin_amdgcn_mfma_f32_16x16x32_bf16(ah0, bh[ks][1], acc01, 0, 0, 0);
        acc10 = __builtin_amdgcn_mfma_f32_16x16x32_bf16(ah1, bh[ks][0], acc10, 0, 0, 0);
        acc11 = __builtin_amdgcn_mfma_f32_16x16x32_bf16(ah1, bh[ks][1], acc11, 0, 0, 0);
        acc00 = __builtin_amdgcn_mfma_f32_16x16x32_bf16(ah0, bl[ks][0], acc00, 0, 0, 0);
        acc01 = __builtin_amdgcn_mfma_f32_16x16x32_bf16(ah0, bl[ks][1], acc01, 0, 0, 0);
        acc10 = __builtin_amdgcn_mfma_f32_16x16x32_bf16(ah1, bl[ks][0], acc10, 0, 0, 0);
        acc11 = __builtin_amdgcn_mfma_f32_16x16x32_bf16(ah1, bl[ks][1], acc11, 0, 0, 0);
        acc00 = __builtin_amdgcn_mfma_f32_16x16x32_bf16(al0, bh[ks][0], acc00, 0, 0, 0);
        acc01 = __builtin_amdgcn_mfma_f32_16x16x32_bf16(al0, bh[ks][1], acc01, 0, 0, 0);
        acc10 = __builtin_amdgcn_mfma_f32_16x16x32_bf16(al1, bh[ks][0], acc10, 0, 0, 0);
        acc11 = __builtin_amdgcn_mfma_f32_16x16x32_bf16(al1, bh[ks][1], acc11, 0, 0, 0);
    }

#pragma unroll
    for (int reg = 0; reg < 4; ++reg) {
        int row0g = Rbase + r0 + quad * 4 + reg;
        if (row0g < M) {
            float sc = scale[row0g];
            C[(size_t)row0g * NOUT + Cbase + c0 + m]      = f2bf(acc00[reg] * sc);
            C[(size_t)row0g * NOUT + Cbase + c0 + 16 + m] = f2bf(acc01[reg] * sc);
        }
        int row1g = row0g + 16;
        if (row1g < M) {
            float sc = scale[row1g];
            C[(size_t)row1g * NOUT + Cbase + c0 + m]      = f2bf(acc10[reg] * sc);
            C[(size_t)row1g * NOUT + Cbase + c0 + 16 + m] = f2bf(acc11[reg] * sc);
        }
    }
}

// ---------- Gather aggregation: half-wave row gather, 2 nodes per wave ------
// 32 lanes x ushort4 (8 B) = one full 256 B row per half-wave.
// Joint phase 4-deep: 8 rows in flight per half (16/wave).
__global__ __launch_bounds__(256) void aggregate128_kernel(
    const int* __restrict__ rowoff, const int* __restrict__ csr_src,
    const float* __restrict__ dis, const unsigned short* __restrict__ tp,
    const float* __restrict__ bias, float* __restrict__ hout, int n) {
    int wid = (blockIdx.x * 256 + threadIdx.x) >> 6;
    int lane = threadIdx.x & 63;
    int h = lane >> 5, lc = lane & 31;
    int n0 = wid * 2;
    if (n0 >= n) return;
    int n1 = n0 + 1;
    bool has1 = (n1 < n);

    float a0[4] = {0.f, 0.f, 0.f, 0.f};
    float a1[4] = {0.f, 0.f, 0.f, 0.f};

#define ROW128(node) (*((const ushort4*)(tp + (size_t)(node) * 128) + lc))
#define ACC(a, u) { a[0] += bf2f(u.x); a[1] += bf2f(u.y); a[2] += bf2f(u.z); a[3] += bf2f(u.w); }

    if (h == 0) { ushort4 u = ROW128(n0); ACC(a0, u); }
    else if (has1) { ushort4 u = ROW128(n1); ACC(a1, u); }

    int mid = rowoff[n0 + 1];
    int i0 = rowoff[n0] + h;
    int i1 = mid + h;
    int end1 = has1 ? rowoff[n1 + 1] : mid;

    // 4-deep joint: 8 rows in flight per half
    while (i0 + 6 < mid && i1 + 6 < end1) {
        int p0 = csr_src[i0], p1 = csr_src[i0 + 2], p2 = csr_src[i0 + 4], p3 = csr_src[i0 + 6];
        int q0 = csr_src[i1], q1 = csr_src[i1 + 2], q2 = csr_src[i1 + 4], q3 = csr_src[i1 + 6];
        ushort4 u0 = ROW128(p0), u1 = ROW128(p1), u2 = ROW128(p2), u3 = ROW128(p3);
        ushort4 v0 = ROW128(q0), v1 = ROW128(q1), v2 = ROW128(q2), v3 = ROW128(q3);
        ACC(a0, u0); ACC(a0, u1); ACC(a0, u2); ACC(a0, u3);
        ACC(a1, v0); ACC(a1, v1); ACC(a1, v2); ACC(a1, v3);
        i0 += 8; i1 += 8;
    }
    // 2-deep joint
    while (i0 + 2 < mid && i1 + 2 < end1) {
        int p0 = csr_src[i0], p1 = csr_src[i0 + 2];
        int q0 = csr_src[i1], q1 = csr_src[i1 + 2];
        ushort4 u0 = ROW128(p0), u1 = ROW128(p1);
        ushort4 v0 = ROW128(q0), v1 = ROW128(q1);
        ACC(a0, u0); ACC(a0, u1);
        ACC(a1, v0); ACC(a1, v1);
        i0 += 4; i1 += 4;
    }
    // drains
    for (; i0 + 2 < mid; i0 += 4) {
        int p0 = csr_src[i0], p1 = csr_src[i0 + 2];
        ushort4 u0 = ROW128(p0), u1 = ROW128(p1);
        ACC(a0, u0); ACC(a0, u1);
    }
    for (; i0 < mid; i0 += 2) { ushort4 u = ROW128(csr_src[i0]); ACC(a0, u); }
    for (; i1 + 2 < end1; i1 += 4) {
        int q0 = csr_src[i1], q1 = csr_src[i1 + 2];
        ushort4 v0 = ROW128(q0), v1 = ROW128(q1);
        ACC(a1, v0); ACC(a1, v1);
    }
    for (; i1 < end1; i1 += 2) { ushort4 v = ROW128(csr_src[i1]); ACC(a1, v); }
#undef ROW128
#undef ACC

#pragma unroll
    for (int j = 0; j < 4; ++j) {
        a0[j] += __shfl_xor(a0[j], 32);
        a1[j] += __shfl_xor(a1[j], 32);
    }

    float4 b = ((const float4*)bias)[lc];
    if (h == 0) {
        float dd = dis[n0];
        float4 r;
        r.x = fmaxf(a0[0] * dd + b.x, 0.f);
        r.y = fmaxf(a0[1] * dd + b.y, 0.f);
        r.z = fmaxf(a0[2] * dd + b.z, 0.f);
        r.w = fmaxf(a0[3] * dd + b.w, 0.f);
        ((float4*)(hout + (size_t)n0 * 128))[lc] = r;
    } else if (has1) {
        float dd = dis[n1];
        float4 r;
        r.x = fmaxf(a1[0] * dd + b.x, 0.f);
        r.y = fmaxf(a1[1] * dd + b.y, 0.f);
        r.z = fmaxf(a1[2] * dd + b.z, 0.f);
        r.w = fmaxf(a1[3] * dd + b.w, 0.f);
        ((float4*)(hout + (size_t)n1 * 128))[lc] = r;
    }
}

// F=64 + fused head. 32 lanes x ushort2 (4 B) = one 128 B row per half.
__global__ __launch_bounds__(256) void aggregate64_head_kernel(
    const int* __restrict__ rowoff, const int* __restrict__ csr_src,
    const float* __restrict__ dis, const unsigned short* __restrict__ tp,
    const float* __restrict__ bias, const float* __restrict__ Wout,
    const float* __restrict__ bout, float* __restrict__ hout,
    float* __restrict__ out, int n) {
    int wid = (blockIdx.x * 256 + threadIdx.x) >> 6;
    int lane = threadIdx.x & 63;
    int h = lane >> 5, lc = lane & 31;
    int n0 = wid * 2;
    if (n0 >= n) return;
    int n1 = n0 + 1;
    bool has1 = (n1 < n);

    float a0[2] = {0.f, 0.f};
    float a1[2] = {0.f, 0.f};

#define ROW64(node) (*((const ushort2*)(tp + (size_t)(node) * 64) + lc))
#define ACC2(a, u) { a[0] += bf2f(u.x); a[1] += bf2f(u.y); }

    if (h == 0) { ushort2 u = ROW64(n0); ACC2(a0, u); }
    else if (has1) { ushort2 u = ROW64(n1); ACC2(a1, u); }

    int mid = rowoff[n0 + 1];
    int i0 = rowoff[n0] + h;
    int i1 = mid + h;
    int end1 = has1 ? rowoff[n1 + 1] : mid;

    while (i0 + 6 < mid && i1 + 6 < end1) {
        int p0 = csr_src[i0], p1 = csr_src[i0 + 2], p2 = csr_src[i0 + 4], p3 = csr_src[i0 + 6];
        int q0 = csr_src[i1], q1 = csr_src[i1 + 2], q2 = csr_src[i1 + 4], q3 = csr_src[i1 + 6];
        ushort2 u0 = ROW64(p0), u1 = ROW64(p1), u2 = ROW64(p2), u3 = ROW64(p3);
        ushort2 v0 = ROW64(q0), v1 = ROW64(q1), v2 = ROW64(q2), v3 = ROW64(q3);
        ACC2(a0, u0); ACC2(a0, u1); ACC2(a0, u2); ACC2(a0, u3);
        ACC2(a1, v0); ACC2(a1, v1); ACC2(a1, v2); ACC2(a1, v3);
        i0 += 8; i1 += 8;
    }
    while (i0 + 2 < mid && i1 + 2 < end1) {
        int p0 = csr_src[i0], p1 = csr_src[i0 + 2];
        int q0 = csr_src[i1], q1 = csr_src[i1 + 2];
        ushort2 u0 = ROW64(p0), u1 = ROW64(p1);
        ushort2 v0 = ROW64(q0), v1 = ROW64(q1);
        ACC2(a0, u0); ACC2(a0, u1);
        ACC2(a1, v0); ACC2(a1, v1);
        i0 += 4; i1 += 4;
    }
    for (; i0 < mid; i0 += 2) { ushort2 u = ROW64(csr_src[i0]); ACC2(a0, u); }
    for (; i1 < end1; i1 += 2) { ushort2 v = ROW64(csr_src[i1]); ACC2(a1, v); }
#undef ROW64
#undef ACC2

#pragma unroll
    for (int j = 0; j < 2; ++j) {
        a0[j] += __shfl_xor(a0[j], 32);
        a1[j] += __shfl_xor(a1[j], 32);
    }

    int node = h ? n1 : n0;
    float* ap = h ? a1 : a0;
    bool valid = (h == 0) || has1;
    float2 hv = make_float2(0.f, 0.f);
    if (valid) {
        float dd = dis[node];
        float2 b = ((const float2*)bias)[lc];
        hv.x = ap[0] * dd + b.x;
        hv.y = ap[1] * dd + b.y;
        ((float2*)(hout + (size_t)node * 64))[lc] = hv;
    }
    float2 wv = ((const float2*)Wout)[lc];
    float p = valid ? (hv.x * wv.x + hv.y * wv.y) : 0.f;
#pragma unroll
    for (int off = 16; off > 0; off >>= 1) p += __shfl_down(p, off);
    if (lc == 0 && valid) out[node] = p + bout[0];
}

extern "C" void kernel_launch(void* const* d_in, const int* in_sizes, int n_in,
                              void* d_out, int out_size, void* d_ws, size_t ws_size,
                              hipStream_t stream) {
    const float* x    = (const float*)d_in[0];
    const int*   ei   = (const int*)d_in[1];  // [2, E] flat: src then dst
    const float* W1   = (const float*)d_in[2];
    const float* b1   = (const float*)d_in[3];
    const float* Wh   = (const float*)d_in[4];
    const float* bh   = (const float*)d_in[5];
    const float* W2   = (const float*)d_in[6];
    const float* b2   = (const float*)d_in[7];
    const float* Wout = (const float*)d_in[8];
    const float* bout = (const float*)d_in[9];

    const int N = N_NODES;
    const int E = N_EDGES;
    const int* srcv = ei;
    const int* dstv = ei + E;

    float* out  = (float*)d_out;            // [N]
    float* hout = (float*)d_out + N;        // [N x 64]

    char* ws = (char*)d_ws;
    int*   H       = (int*)ws;                          ws += sizeof(int) * NBUCK * GB;
    int*   bsum    = (int*)ws;                          ws += sizeof(int) * NBUCK;
    int*   bstart  = (int*)ws;                          ws += sizeof(int) * (NBUCK + 1);
    int*   rowoff  = (int*)ws;                          ws += sizeof(int) * (N + 1);
    unsigned int* P = (unsigned int*)ws;                ws += sizeof(unsigned int) * E;
    int*   csr_src = (int*)ws;                          ws += sizeof(int) * E;
    float* dis     = (float*)ws;                        ws += sizeof(float) * N;
    unsigned short* W1thi = (unsigned short*)ws;        ws += sizeof(unsigned short) * 128 * 128;
    unsigned short* W1tlo = (unsigned short*)ws;        ws += sizeof(unsigned short) * 128 * 128;
    unsigned short* Whthi = (unsigned short*)ws;        ws += sizeof(unsigned short) * 128 * 128;
    unsigned short* Whtlo = (unsigned short*)ws;        ws += sizeof(unsigned short) * 128 * 128;
    unsigned short* W2thi = (unsigned short*)ws;        ws += sizeof(unsigned short) * 64 * 128;
    unsigned short* W2tlo = (unsigned short*)ws;        ws += sizeof(unsigned short) * 64 * 128;
    unsigned short* bufT  = (unsigned short*)ws;        ws += sizeof(unsigned short) * (size_t)N * 128;
    float* bufH    = (float*)ws;                        // N*128 fp32

    // --- W prep (fused, bf16 hi/lo transposed) ---
    wprep_all_kernel<<<160, 256, 0, stream>>>(W1, Wh, W2, W1thi, W1tlo, Whthi, Whtlo, W2thi, W2tlo);

    // --- CSR build (two-level counting sort, hierarchical scan, packed P) ---
    hist_kernel<<<GB, 256, 0, stream>>>(dstv, H, E);
    scan1_kernel<<<NBUCK, 256, 0, stream>>>(H, bsum);
    scan2_kernel<<<1, 256, 0, stream>>>(bsum, bstart, rowoff + N);
    partition_kernel<<<GB, 256, 0, stream>>>(srcv, dstv, H, bstart, P, E);
    bucket_csr_kernel<<<NBUCK, 256, 0, stream>>>(P, bstart, rowoff, dis, csr_src, N);

    const int aggBlocks = ((N + 1) / 2 * 64 + 255) / 256;  // 2 nodes per wave
    const int gemmRows = (N + 63) / 64;                    // 782

    // --- layer 1: h1 = relu(agg(x@W1) + b1) ---
    gemm_mfma_kernel<128><<<dim3(gemmRows, 2), 256, 0, stream>>>(x, W1thi, W1tlo, dis, bufT, N);
    aggregate128_kernel<<<aggBlocks, 256, 0, stream>>>(rowoff, csr_src, dis, bufT, b1, bufH, N);

    // --- layer 2: h2 = relu(agg(h1@Wh) + bh) ---
    gemm_mfma_kernel<128><<<dim3(gemmRows, 2), 256, 0, stream>>>(bufH, Whthi, Whtlo, dis, bufT, N);
    aggregate128_kernel<<<aggBlocks, 256, 0, stream>>>(rowoff, csr_src, dis, bufT, bh, bufH, N);

    // --- layer 3 + head: h3 = agg(h2@W2) + b2 ; out = h3@Wout + bout ---
    gemm_mfma_kernel<64><<<dim3(gemmRows, 1), 256, 0, stream>>>(bufH, W2thi, W2tlo, dis, bufT, N);
    aggregate64_head_kernel<<<aggBlocks, 256, 0, stream>>>(
        rowoff, csr_src, dis, bufT, b2, Wout, bout, hout, out, N);
}